// Round 2
// baseline (223.524 us; speedup 1.0000x reference)
//
#include <hip/hip_runtime.h>
#include <stdint.h>

// ---- types ----
typedef __attribute__((ext_vector_type(8))) short short8;   // 8 bf16 (4 VGPRs)
typedef __attribute__((ext_vector_type(4))) float f32x4;    // MFMA acc
typedef unsigned short u16;

#define LOG2E 1.44269504088896340736f

// B=2, S=2048, E=1024, H=16, DK=64
#define SEQ 2048
#define EMB 1024
#define NH 16
#define DK 64
#define MTOT 4096   // B*S

__device__ __forceinline__ u16 f2bf(float f) {
  union { float f; unsigned int u; } x; x.f = f;
  unsigned int r = x.u + 0x7fffu + ((x.u >> 16) & 1u);  // RNE
  return (u16)(r >> 16);
}

// async global->LDS, 16B per lane. LDS dest = wave-uniform base + lane*16.
__device__ __forceinline__ void gload_lds16(const void* g, void* l) {
  __builtin_amdgcn_global_load_lds(
      (const __attribute__((address_space(1))) unsigned int*)g,
      (__attribute__((address_space(3))) unsigned int*)l,
      16, 0, 0);
}

// ---------------- fp32 -> bf16 convert ----------------
__global__ __launch_bounds__(256) void cvt_f32_bf16(const float* __restrict__ s,
                                                    u16* __restrict__ d, int n4) {
  int i = blockIdx.x * 256 + threadIdx.x;
  if (i < n4) {
    float4 v = ((const float4*)s)[i];
    ushort4 o;
    o.x = f2bf(v.x); o.y = f2bf(v.y); o.z = f2bf(v.z); o.w = f2bf(v.w);
    ((ushort4*)d)[i] = o;
  }
}

// ---------------- GEMM core: C[M,N] = A[M,K] @ W[N,K]^T + bias ----------------
// BM=BN=128, BK=64, 256 threads = 4 waves (2x2), each wave 64x64 (4x4 frags).
// MODE 0: store bf16 into [B,H,S,DK] head layout. MODE 1: store fp32 flat [M,N].
template <int MODE>
__device__ __forceinline__ void gemm_core(const u16* __restrict__ A,
                                          const u16* __restrict__ W,
                                          const float* __restrict__ bias,
                                          void* __restrict__ dst,
                                          int m0, int n0,
                                          u16* As, u16* Bs) {
  const int K = EMB;
  int tid = threadIdx.x, lane = tid & 63, wid = tid >> 6;
  int g = lane >> 4, l15 = lane & 15;
  int wr = wid >> 1, wc = wid & 1;

  f32x4 acc[4][4];
#pragma unroll
  for (int mi = 0; mi < 4; ++mi)
#pragma unroll
    for (int ni = 0; ni < 4; ++ni) acc[mi][ni] = (f32x4)(0.0f);

  for (int kt = 0; kt < K / 64; ++kt) {
    int k0 = kt * 64;
    // stage A and B tiles (16KB each) via global_load_lds, 1KB per wave-instr
#pragma unroll
    for (int i = 0; i < 4; ++i) {
      int off = (wid * 4 + i) * 1024;          // byte offset into tile
      int elem = (off >> 1) + lane * 8;        // bf16 element index
      int row = elem >> 6, col = elem & 63;
      gload_lds16(A + (size_t)(m0 + row) * K + k0 + col, (char*)As + off);
      gload_lds16(W + (size_t)(n0 + row) * K + k0 + col, (char*)Bs + off);
    }
    __syncthreads();  // drains vmcnt
#pragma unroll
    for (int kk = 0; kk < 2; ++kk) {
      short8 af[4], bf[4];
#pragma unroll
      for (int mi = 0; mi < 4; ++mi)
        af[mi] = *(const short8*)&As[(wr * 64 + mi * 16 + l15) * 64 + kk * 32 + 8 * g];
#pragma unroll
      for (int ni = 0; ni < 4; ++ni)
        bf[ni] = *(const short8*)&Bs[(wc * 64 + ni * 16 + l15) * 64 + kk * 32 + 8 * g];
#pragma unroll
      for (int mi = 0; mi < 4; ++mi)
#pragma unroll
        for (int ni = 0; ni < 4; ++ni)
          acc[mi][ni] = __builtin_amdgcn_mfma_f32_16x16x32_bf16(af[mi], bf[ni],
                                                                acc[mi][ni], 0, 0, 0);
    }
    __syncthreads();
  }

  // epilogue: D layout col=lane&15, row=(lane>>4)*4+j  [m89-verified]
#pragma unroll
  for (int ni = 0; ni < 4; ++ni) {
    int n_g = n0 + wc * 64 + ni * 16 + l15;
    float bv = bias[n_g];
#pragma unroll
    for (int mi = 0; mi < 4; ++mi) {
#pragma unroll
      for (int j = 0; j < 4; ++j) {
        int m_g = m0 + wr * 64 + mi * 16 + 4 * g + j;
        float v = acc[mi][ni][j] + bv;
        if (MODE == 0) {
          int b = m_g >> 11, s = m_g & (SEQ - 1);
          int h = n_g >> 6, d = n_g & 63;
          ((u16*)dst)[((((size_t)b * NH + h) * SEQ + s) << 6) + d] = f2bf(v);
        } else {
          ((float*)dst)[(size_t)m_g * EMB + n_g] = v;
        }
      }
    }
  }
}

__global__ __launch_bounds__(256, 2) void gemm_qkv(const u16* __restrict__ Aall,
                                                   const u16* __restrict__ Wall,
                                                   const float* __restrict__ bq,
                                                   const float* __restrict__ bk,
                                                   const float* __restrict__ bv,
                                                   u16* __restrict__ QKVh) {
  __shared__ __align__(16) u16 As[128 * 64];
  __shared__ __align__(16) u16 Bs[128 * 64];
  int z = blockIdx.z;
  const u16* A = Aall + (size_t)z * MTOT * EMB;
  const u16* W = Wall + (size_t)z * EMB * EMB;
  const float* bias = (z == 0) ? bq : ((z == 1) ? bk : bv);
  u16* dst = QKVh + (size_t)z * MTOT * EMB;
  gemm_core<0>(A, W, bias, dst, blockIdx.y * 128, blockIdx.x * 128, As, Bs);
}

__global__ __launch_bounds__(256, 2) void gemm_out(const u16* __restrict__ X,
                                                   const u16* __restrict__ Wo,
                                                   const float* __restrict__ bo,
                                                   float* __restrict__ out) {
  __shared__ __align__(16) u16 As[128 * 64];
  __shared__ __align__(16) u16 Bs[128 * 64];
  gemm_core<1>(X, Wo, bo, out, blockIdx.y * 128, blockIdx.x * 128, As, Bs);
}

// ---------------- flash attention (causal) ----------------
// grid (S/64, B*H), 256 threads = 4 waves, wave w owns q rows [q0+16w, q0+16w+16)
// K frags direct from global (L2/L3-resident); V transposed in LDS; P via LDS.
__global__ __launch_bounds__(256, 2) void flash_attn(const u16* __restrict__ Qh,
                                                     const u16* __restrict__ Kh,
                                                     const u16* __restrict__ Vh,
                                                     u16* __restrict__ X) {
  __shared__ __align__(16) u16 Vt[64][72];      // [d][kv], pad->144B rows
  __shared__ __align__(16) u16 Ps[4][16][72];   // per-wave P [q][kv]

  int tid = threadIdx.x, lane = tid & 63, wid = tid >> 6;
  int g = lane >> 4, l15 = lane & 15;
  int qt = gridDim.x - 1 - blockIdx.x;          // heavy blocks first
  int bh = blockIdx.y;
  int q0 = qt * 64;
  int qw = q0 + wid * 16;

  // Q fragments: rows qw+l15; two k-halves at elements +0 and +32 (qp[0], qp[4])
  const short8* qp = (const short8*)(Qh + ((size_t)bh * SEQ + qw + l15) * DK + 8 * g);
  short8 aq0 = qp[0];
  short8 aq1 = qp[4];  // +32 bf16 elements (4 short8's), NOT qp[2]

  f32x4 oacc[4];
  float m_run[4], l_run[4];
#pragma unroll
  for (int j = 0; j < 4; ++j) { m_run[j] = -1e30f; l_run[j] = 0.0f; }
#pragma unroll
  for (int c = 0; c < 4; ++c) oacc[c] = (f32x4)(0.0f);

  for (int t = 0; t <= qt; ++t) {
    int kv0 = t * 64;
    __syncthreads();  // protect Vt from previous tile's PV reads
    {
      int d = lane;  // 0..63 within wave
#pragma unroll
      for (int it = 0; it < 2; ++it) {
        int kvb = wid * 8 + it * 32;
        short8 tmp;
#pragma unroll
        for (int i = 0; i < 8; ++i)
          tmp[i] = (short)Vh[((size_t)bh * SEQ + kv0 + kvb + i) * DK + d];
        *(short8*)&Vt[d][kvb] = tmp;
      }
    }
    __syncthreads();

    // QK^T: scores 16x64 per wave, 4 col-chunks
    f32x4 sc[4];
#pragma unroll
    for (int c = 0; c < 4; ++c) {
      const short8* kp =
          (const short8*)(Kh + ((size_t)bh * SEQ + kv0 + c * 16 + l15) * DK + 8 * g);
      f32x4 z = (f32x4)(0.0f);
      z = __builtin_amdgcn_mfma_f32_16x16x32_bf16(aq0, kp[0], z, 0, 0, 0);
      z = __builtin_amdgcn_mfma_f32_16x16x32_bf16(aq1, kp[4], z, 0, 0, 0);
      sc[c] = z;
    }

    bool diag = (t == qt);
    // scale + causal mask + row max (reduce over 16 lanes in group)
    float vmax[4];
#pragma unroll
    for (int j = 0; j < 4; ++j) {
#pragma unroll
      for (int c = 0; c < 4; ++c) {
        float s = sc[c][j] * 0.125f;
        if (diag && (kv0 + c * 16 + l15 > qw + 4 * g + j)) s = -1e30f;
        sc[c][j] = s;
      }
      float vm = fmaxf(fmaxf(sc[0][j], sc[1][j]), fmaxf(sc[2][j], sc[3][j]));
      vm = fmaxf(vm, __shfl_xor(vm, 1));
      vm = fmaxf(vm, __shfl_xor(vm, 2));
      vm = fmaxf(vm, __shfl_xor(vm, 4));
      vm = fmaxf(vm, __shfl_xor(vm, 8));
      vmax[j] = vm;
    }
#pragma unroll
    for (int j = 0; j < 4; ++j) {
      float mnew = fmaxf(m_run[j], vmax[j]);
      float alpha = exp2f((m_run[j] - mnew) * LOG2E);
      float rs = 0.0f;
#pragma unroll
      for (int c = 0; c < 4; ++c) {
        float p = exp2f((sc[c][j] - mnew) * LOG2E);
        sc[c][j] = p;
        rs += p;
      }
      rs += __shfl_xor(rs, 1);
      rs += __shfl_xor(rs, 2);
      rs += __shfl_xor(rs, 4);
      rs += __shfl_xor(rs, 8);
      l_run[j] = l_run[j] * alpha + rs;
      m_run[j] = mnew;
#pragma unroll
      for (int c2 = 0; c2 < 4; ++c2) oacc[c2][j] *= alpha;
    }

    // P -> LDS (bf16), per-wave buffer, no cross-wave barrier needed
#pragma unroll
    for (int c = 0; c < 4; ++c)
#pragma unroll
      for (int j = 0; j < 4; ++j)
        Ps[wid][4 * g + j][c * 16 + l15] = f2bf(sc[c][j]);

    // PV: O[16q x 64d] += P[16q x 64kv] @ V[64kv x 64d]
    short8 ap[2];
    ap[0] = *(const short8*)&Ps[wid][l15][8 * g];
    ap[1] = *(const short8*)&Ps[wid][l15][32 + 8 * g];
#pragma unroll
    for (int c2 = 0; c2 < 4; ++c2) {
#pragma unroll
      for (int ks = 0; ks < 2; ++ks) {
        short8 bv = *(const short8*)&Vt[c2 * 16 + l15][ks * 32 + 8 * g];
        oacc[c2] = __builtin_amdgcn_mfma_f32_16x16x32_bf16(ap[ks], bv, oacc[c2], 0, 0, 0);
      }
    }
  }

  // epilogue: X[b][s][h*64+d] bf16
  int b = bh >> 4, h = bh & 15;
#pragma unroll
  for (int j = 0; j < 4; ++j) {
    float inv = 1.0f / l_run[j];
    int s = q0 + wid * 16 + 4 * g + j;
#pragma unroll
    for (int c2 = 0; c2 < 4; ++c2) {
      int d = c2 * 16 + l15;
      X[((size_t)b * SEQ + s) * EMB + h * 64 + d] = f2bf(oacc[c2][j] * inv);
    }
  }
}

// ---------------- host ----------------
extern "C" void kernel_launch(void* const* d_in, const int* in_sizes, int n_in,
                              void* d_out, int out_size, void* d_ws, size_t ws_size,
                              hipStream_t stream) {
  const float* q  = (const float*)d_in[0];
  const float* k  = (const float*)d_in[1];
  const float* v  = (const float*)d_in[2];
  const float* wq = (const float*)d_in[4];
  const float* bq = (const float*)d_in[5];
  const float* wk = (const float*)d_in[6];
  const float* bk = (const float*)d_in[7];
  const float* wv = (const float*)d_in[8];
  const float* bv = (const float*)d_in[9];
  const float* wo = (const float*)d_in[10];
  const float* bo = (const float*)d_in[11];

  u16* Aall = (u16*)d_ws;                                 // 3 x [4096,1024] bf16
  u16* Wall = Aall + (size_t)3 * MTOT * EMB;              // 4 x [1024,1024] bf16
  u16* QKVh = Wall + (size_t)4 * EMB * EMB;               // 3 x [B,H,S,64] bf16
  u16* Xb   = QKVh + (size_t)3 * MTOT * EMB;              // [4096,1024] bf16

  // converts: q,k,v (4096*1024 each), 4 weights (1024*1024 each)
  int nqkv4 = MTOT * EMB / 4;   // 1,048,576
  int nw4 = EMB * EMB / 4;      // 262,144
  cvt_f32_bf16<<<nqkv4 / 256, 256, 0, stream>>>(q, Aall, nqkv4);
  cvt_f32_bf16<<<nqkv4 / 256, 256, 0, stream>>>(k, Aall + (size_t)MTOT * EMB, nqkv4);
  cvt_f32_bf16<<<nqkv4 / 256, 256, 0, stream>>>(v, Aall + (size_t)2 * MTOT * EMB, nqkv4);
  cvt_f32_bf16<<<nw4 / 256, 256, 0, stream>>>(wq, Wall, nw4);
  cvt_f32_bf16<<<nw4 / 256, 256, 0, stream>>>(wk, Wall + (size_t)EMB * EMB, nw4);
  cvt_f32_bf16<<<nw4 / 256, 256, 0, stream>>>(wv, Wall + (size_t)2 * EMB * EMB, nw4);
  cvt_f32_bf16<<<nw4 / 256, 256, 0, stream>>>(wo, Wall + (size_t)3 * EMB * EMB, nw4);

  // QKV projections -> head layout
  dim3 gq(EMB / 128, MTOT / 128, 3);
  gemm_qkv<<<gq, 256, 0, stream>>>(Aall, Wall, bq, bk, bv, QKVh);

  // flash attention -> Xb [4096,1024] bf16
  const u16* Qh = QKVh;
  const u16* Kh = QKVh + (size_t)MTOT * EMB;
  const u16* Vh = QKVh + (size_t)2 * MTOT * EMB;
  dim3 ga(SEQ / 64, 2 * NH);
  flash_attn<<<ga, 256, 0, stream>>>(Qh, Kh, Vh, Xb);

  // output projection -> fp32 d_out
  dim3 go(EMB / 128, MTOT / 128);
  gemm_out<<<go, 256, 0, stream>>>(Xb, Wall + (size_t)3 * EMB * EMB, bo, (float*)d_out);
}